// Round 5
// baseline (40.900 us; speedup 1.0000x reference)
//
#include <hip/hip_runtime.h>

constexpr int C   = 640;
constexpr int HW  = 25;
constexpr int PSTRIDE = 832;     // ws floats per gram block: 625 G + 100 csum + 100 csum2 (+pad)

__device__ __forceinline__ float rl(float x, int lane) {
  return __uint_as_float(__builtin_amdgcn_readlane(__float_as_uint(x), lane));
}

// ---------- Kernel 1: partial Gram (160 channels) + partial moments ----------
__global__ __launch_bounds__(256, 5) void emd_gram(
    const float* __restrict__ support, const float* __restrict__ query,
    float* __restrict__ part)
{
  const int bid = blockIdx.x;
  const int n = bid >> 2, h = bid & 3;
  const int tid = threadIdx.x;

  __shared__ union alignas(16) {
    float st[8000];           // [2 mats][160 ch][25 hw] = 32000 B
    float Gp[10 * 625];       // 25000 B partial-Gram alias
  } sa;

  const size_t base = (size_t)n * (C * HW) + (size_t)h * (160 * HW);
  const float4* Qg = reinterpret_cast<const float4*>(query + base);
  const float4* Sg = reinterpret_cast<const float4*>(support + base);

  float acc[5][5] = {{0.f}};
  const int tile = tid % 25, grp = tid / 25;          // grp 0..9 (tid<250)
  const int u0 = (tile / 5) * 5, v0 = (tile % 5) * 5;
  const int mmat = tid / 50, mhalf = (tid / 25) & 1, mcol = tid % 25; // tid<100
  float csum = 0.f, csum2 = 0.f;

  #pragma unroll
  for (int p = 0; p < 8; ++p) {
    int idx = tid + p * 256;
    if (idx < 2000) {
      float4 val = (idx < 1000) ? Qg[idx] : Sg[idx - 1000];
      reinterpret_cast<float4*>(sa.st)[idx] = val;
    }
  }
  __syncthreads();

  if (tid < 250) {
    const float* qb = sa.st + grp * 16 * HW;
    const float* sb = sa.st + 4000 + grp * 16 * HW;
    #pragma unroll 2
    for (int cc = 0; cc < 16; cc += 2) {
      float q0[5], q1[5], s0[5], s1[5];
      #pragma unroll
      for (int i = 0; i < 5; ++i) {
        q0[i] = qb[cc * HW + u0 + i];
        q1[i] = qb[cc * HW + HW + u0 + i];
        s0[i] = sb[cc * HW + v0 + i];
        s1[i] = sb[cc * HW + HW + v0 + i];
      }
      #pragma unroll
      for (int i = 0; i < 5; ++i)
        #pragma unroll
        for (int j = 0; j < 5; ++j) {
          acc[i][j] = fmaf(q0[i], s0[j], acc[i][j]);
          acc[i][j] = fmaf(q1[i], s1[j], acc[i][j]);
        }
    }
  }
  if (tid < 100) {   // per-column moments: 2 mats x 2 halves(80ch) x 25 cols
    const float* mb = sa.st + mmat * 4000 + mhalf * 80 * HW;
    #pragma unroll 4
    for (int c = 0; c < 80; ++c) {
      float x = mb[c * HW + mcol];
      csum += x;
      csum2 = fmaf(x, x, csum2);
    }
  }
  __syncthreads();   // staging reads done; safe to alias Gp

  if (tid < 250) {
    #pragma unroll
    for (int i = 0; i < 5; ++i)
      #pragma unroll
      for (int j = 0; j < 5; ++j)
        sa.Gp[grp * 625 + (u0 + i) * 25 + (v0 + j)] = acc[i][j];
  }
  __syncthreads();

  float* w = part + (size_t)bid * PSTRIDE;
  for (int p = tid; p < 625; p += 256) {
    float g = 0.f;
    #pragma unroll
    for (int gg = 0; gg < 10; ++gg) g += sa.Gp[gg * 625 + p];
    w[p] = g;
  }
  if (tid < 100) {
    w[625 + tid] = csum;     // tid = mmat*50 + mhalf*25 + mcol
    w[725 + tid] = csum2;
  }
}

// ---------- Kernel 2: combine partials + sim + Sinkhorn, one wave/sample ----------
__global__ __launch_bounds__(64) void emd_sink(
    const float* __restrict__ part, float* __restrict__ out)
{
  const int n    = blockIdx.x;
  const int tid  = threadIdx.x;
  const float* P = part + (size_t)(4 * n) * PSTRIDE;

  __shared__ float G[625];
  __shared__ float sQ[25], sS[25], nq[25], ns[25], am[25], bm[25];
  __shared__ float scal[2];

  for (int p = tid; p < 625; p += 64)
    G[p] = (P[p] + P[PSTRIDE + p]) + (P[2 * PSTRIDE + p] + P[3 * PSTRIDE + p]);
  if (tid < 50) {
    int mat = tid / 25, col = tid % 25;
    int o = 625 + mat * 50 + col;
    float s = 0.f, ss = 0.f;
    #pragma unroll
    for (int hh = 0; hh < 4; ++hh) {
      const float* Ph = P + (size_t)hh * PSTRIDE;
      s  += Ph[o]       + Ph[o + 25];
      ss += Ph[o + 100] + Ph[o + 125];
    }
    float var = ss - s * s * (1.f / C);
    float nrm = fmaxf(sqrtf(fmaxf(var, 0.f)), 1e-8f);
    if (mat == 0) { sQ[col] = s; nq[col] = nrm; }
    else          { sS[col] = s; ns[col] = nrm; }
  }
  __syncthreads();

  if (tid < 25) {
    float s = 0.f;
    #pragma unroll
    for (int j = 0; j < 25; ++j) s += G[tid * 25 + j];
    am[tid] = fmaxf(s * (1.f / 25.f), 0.f) + 0.001f + 1e-5f;
  } else if (tid >= 32 && tid < 57) {
    int v = tid - 32;
    float s = 0.f;
    #pragma unroll
    for (int u = 0; u < 25; ++u) s += G[u * 25 + v];
    bm[v] = fmaxf(s * (1.f / 25.f), 0.f) + 0.001f + 1e-5f;
  }
  __syncthreads();
  if (tid == 0) {
    float s0 = 0.f, s1 = 0.f;
    #pragma unroll
    for (int i = 0; i < 25; ++i) { s0 += am[i]; s1 += bm[i]; }
    scal[0] = 25.f / s0; scal[1] = 25.f / s1;
  }
  for (int p = tid; p < 625; p += 64) {   // sim in place
    int u = p / 25, v = p % 25;
    float cov = G[p] - sQ[u] * sS[v] * (1.f / C);
    G[p] = cov / (nq[u] * ns[v]);
  }
  __syncthreads();

  const int lane = tid;
  const int u = (lane < 25) ? lane : 24;
  float simr[25], Krow[25], Kcol[25];
  #pragma unroll
  for (int j = 0; j < 25; ++j) simr[j] = G[u * 25 + j];
  #pragma unroll
  for (int j = 0; j < 25; ++j) Kcol[j] = __expf(-20.f * (1.f - G[j * 25 + u]));
  #pragma unroll
  for (int j = 0; j < 25; ++j) Krow[j] = __expf(-20.f * (1.f - simr[j]));
  const float a_u = am[u] * scal[0], b_u = bm[u] * scal[1];

  float vv = 1.0f, uu = 0.0f, vold = 1.0f;
  #pragma unroll 1
  for (int it = 0; it < 100; ++it) {
    float s0 = 0, s1 = 0, s2 = 0, s3 = 0, s4 = 0;
    #pragma unroll
    for (int j = 0; j < 25; j += 5) {
      s0 = fmaf(Krow[j + 0], rl(vv, j + 0), s0);
      s1 = fmaf(Krow[j + 1], rl(vv, j + 1), s1);
      s2 = fmaf(Krow[j + 2], rl(vv, j + 2), s2);
      s3 = fmaf(Krow[j + 3], rl(vv, j + 3), s3);
      s4 = fmaf(Krow[j + 4], rl(vv, j + 4), s4);
    }
    uu = a_u * __builtin_amdgcn_rcpf(((((s0 + s1) + (s2 + s3)) + s4) + 1e-30f));

    s0 = s1 = s2 = s3 = s4 = 0;
    #pragma unroll
    for (int j = 0; j < 25; j += 5) {
      s0 = fmaf(Kcol[j + 0], rl(uu, j + 0), s0);
      s1 = fmaf(Kcol[j + 1], rl(uu, j + 1), s1);
      s2 = fmaf(Kcol[j + 2], rl(uu, j + 2), s2);
      s3 = fmaf(Kcol[j + 3], rl(uu, j + 3), s3);
      s4 = fmaf(Kcol[j + 4], rl(uu, j + 4), s4);
    }
    vv = b_u * __builtin_amdgcn_rcpf(((((s0 + s1) + (s2 + s3)) + s4) + 1e-30f));

    if ((it & 7) == 7) {
      bool conv = fabsf(vv - vold) <= 1e-5f * fabsf(vv);
      if (__all(conv)) break;
      vold = vv;
    }
  }
  {
    float s0 = 0, s1 = 0, s2 = 0, s3 = 0, s4 = 0;
    #pragma unroll
    for (int j = 0; j < 25; j += 5) {
      s0 = fmaf(Krow[j + 0], rl(vv, j + 0), s0);
      s1 = fmaf(Krow[j + 1], rl(vv, j + 1), s1);
      s2 = fmaf(Krow[j + 2], rl(vv, j + 2), s2);
      s3 = fmaf(Krow[j + 3], rl(vv, j + 3), s3);
      s4 = fmaf(Krow[j + 4], rl(vv, j + 4), s4);
    }
    uu = a_u * __builtin_amdgcn_rcpf(((((s0 + s1) + (s2 + s3)) + s4) + 1e-30f));
  }

  float pr = 0.f;
  if (lane < 25) {
    float t0 = 0.f;
    #pragma unroll
    for (int j = 0; j < 25; ++j)
      t0 = fmaf(simr[j] * Krow[j], rl(vv, j), t0);
    pr = uu * t0;
  }
  #pragma unroll
  for (int off = 32; off; off >>= 1) pr += __shfl_xor(pr, off);
  if (lane == 0) out[n] = pr * 0.5f;   // TEMPERATURE/hw = 12.5/25
}

extern "C" void kernel_launch(void* const* d_in, const int* in_sizes, int n_in,
                              void* d_out, int out_size, void* d_ws, size_t ws_size,
                              hipStream_t stream) {
  const float* support = (const float*)d_in[0];
  const float* query   = (const float*)d_in[1];
  float* out = (float*)d_out;
  const int N = in_sizes[0] / (C * HW);   // 600
  float* partbuf = (float*)d_ws;
  emd_gram<<<dim3(4 * N), dim3(256), 0, stream>>>(support, query, partbuf);
  emd_sink<<<dim3(N),     dim3(64),  0, stream>>>(partbuf, out);
}